// Round 4
// baseline (131.198 us; speedup 1.0000x reference)
//
#include <hip/hip_runtime.h>
#include <cstddef>

// Problem constants (match reference)
#define T_STEPS 32
#define B_SZ    512
#define S_SZ    64
#define F_INPUT 128
#define H1      256
#define H2      256
#define H3      128

typedef _Float16 half_t;
typedef __attribute__((ext_vector_type(8))) _Float16 half8;
typedef __attribute__((ext_vector_type(4))) float   float4v;

#define PREP_SENT 0x1A2B3C4Du   // per-block "weights ready" flag value

// ---------------------------------------------------------------------------
// Weight pre-split + SWIZZLE into MFMA-fragment order (verified exact since
// R6):  hi = f16(w) (flushed if f16-denormal), lo = f16((w - hi) * 2^12)
// Tile (n_tile, k_chunk) = 1024 halfs: [0,512) hi, [512,1024) lo, element
// (lr=n&15, quad=kin>>3, j=kin&7) at (quad*16+lr)*8 + j.
// Wave B-frag load = base + lane*8 -> 1 KB fully coalesced, L2-resident.
// R4 CHANGE: no longer a separate kernel — fused into the mega kernel's
// prologue (1 element/thread), ordered by device-scope flags (see below).
// ---------------------------------------------------------------------------
__device__ inline void split_store_sw(float w, half_t* out, int n, int k, int kchunks) {
    half_t hi = (half_t)w;
    float hif = (float)hi;
    if (fabsf(hif) < 6.103515625e-05f) { hi = (half_t)0.0f; hif = 0.0f; }
    half_t lo = (half_t)((w - hif) * 4096.0f);
    int n_tile = n >> 4, lr = n & 15;
    int k_chunk = k >> 5, kin = k & 31, quad = kin >> 3, j = kin & 7;
    size_t base = (size_t)(n_tile * kchunks + k_chunk) * 1024;
    size_t off  = base + (size_t)((quad << 4) + lr) * 8 + j;
    out[off]       = hi;
    out[off + 512] = lo;
}

// ---------------------------------------------------------------------------
// LDS geometry (unchanged from R7/R9): spk aliases As; 49 KB -> 2 blocks/CU.
// ---------------------------------------------------------------------------
#define CUR_STRIDE 260   // floats; cur tile [32][CUR_STRIDE] (also hist scratch)
#define AS_STRIDE  136   // halfs;  rates  [32][AS_STRIDE]
#define SPK_STRIDE 264   // halfs;  spikes [32][SPK_STRIDE]
#define SMEM_CUR   0                      // 32*260*4 = 33280 B
#define SMEM_AS    33280                  // As: 8704 B  } aliased: max = 16896
#define SMEM_SPK   33280                  // spk: 16896 B}
#define SMEM_TOTAL 50176                  // 49 KB; x2 blocks/CU = 98 KB < 160

// GEMM phase (unchanged from R9): C = sum A*(hi + 2^-12 lo) + bias, depth-1
// W prefetch, per-accumulator MFMA order fixed -> bit-identical across rounds.
template<int KCHUNKS, int NT, int ASTRIDE>
__device__ __forceinline__ void gemm_phase(const half_t* __restrict__ Wsw,
                                           const float*  __restrict__ bias,
                                           const half_t* __restrict__ Als,
                                           float* __restrict__ curT,
                                           int wave, int lane) {
    const int quad = lane >> 4, lr = lane & 15;
    float4v acc_h[2][NT], acc_l[2][NT];
#pragma unroll
    for (int mt = 0; mt < 2; ++mt)
#pragma unroll
        for (int nt = 0; nt < NT; ++nt) {
            acc_h[mt][nt] = (float4v){0.0f, 0.0f, 0.0f, 0.0f};
            acc_l[mt][nt] = (float4v){0.0f, 0.0f, 0.0f, 0.0f};
        }

    half8 wh[NT], wl[NT];
#pragma unroll
    for (int nt = 0; nt < NT; ++nt) {
        const half_t* p = Wsw + ((size_t)(wave * NT + nt) * KCHUNKS) * 1024 + lane * 8;
        wh[nt] = *(const half8*)(p);
        wl[nt] = *(const half8*)(p + 512);
    }

#pragma unroll
    for (int c = 0; c < KCHUNKS; ++c) {
        half8 a0 = *(const half8*)(Als + lr * ASTRIDE        + c * 32 + quad * 8);
        half8 a1 = *(const half8*)(Als + (16 + lr) * ASTRIDE + c * 32 + quad * 8);
        half8 nwh[NT], nwl[NT];
        if (c + 1 < KCHUNKS) {
#pragma unroll
            for (int nt = 0; nt < NT; ++nt) {
                const half_t* p =
                    Wsw + ((size_t)(wave * NT + nt) * KCHUNKS + c + 1) * 1024 + lane * 8;
                nwh[nt] = *(const half8*)(p);
                nwl[nt] = *(const half8*)(p + 512);
            }
        }
#pragma unroll
        for (int nt = 0; nt < NT; ++nt) {
            acc_h[0][nt] = __builtin_amdgcn_mfma_f32_16x16x32_f16(a0, wh[nt], acc_h[0][nt], 0, 0, 0);
            acc_h[1][nt] = __builtin_amdgcn_mfma_f32_16x16x32_f16(a1, wh[nt], acc_h[1][nt], 0, 0, 0);
            acc_l[0][nt] = __builtin_amdgcn_mfma_f32_16x16x32_f16(a0, wl[nt], acc_l[0][nt], 0, 0, 0);
            acc_l[1][nt] = __builtin_amdgcn_mfma_f32_16x16x32_f16(a1, wl[nt], acc_l[1][nt], 0, 0, 0);
        }
#pragma unroll
        for (int nt = 0; nt < NT; ++nt) { wh[nt] = nwh[nt]; wl[nt] = nwl[nt]; }
    }

    // epilogue -> curT (C/D layout: col=lane&15, row=quad*4+reg)
#pragma unroll
    for (int nt = 0; nt < NT; ++nt) {
        int col = wave * NT * 16 + nt * 16 + lr;
        float bj = bias[col];
#pragma unroll
        for (int mt = 0; mt < 2; ++mt) {
            int rbase = mt * 16 + quad * 4;
#pragma unroll
            for (int r = 0; r < 4; ++r) {
                float v = acc_h[mt][nt][r] + 2.44140625e-04f * acc_l[mt][nt][r];
                curT[(rbase + r) * CUR_STRIDE + col] = v + bj;
            }
        }
    }
}

// ---------------------------------------------------------------------------
// Mega kernel: one block = one batch b, 512 threads (8 waves).
// CHANGED vs R3 (single change: prep_w dispatch fused away):
//   Each block preps its 256 weight elements (1/thread, prologue-only; the
//   GEMM phases are untouched — R1/R2 showed regalloc there is fragile).
//   Cross-block ordering via device-scope flags (guide §6 G16 pattern):
//     writer: prep stores -> __syncthreads (drains per-wave vmcnt) ->
//             tid0 RELEASE/AGENT store of flags[b]  (L2 writeback)
//     reader: before GEMM1, thread t spins flags[t] with RELAXED/AGENT loads
//             (sc1: not served by stale local L2) -> __syncthreads ->
//             ACQUIRE/AGENT fence (L1/L2 inv) -> ws reads
//   No deadlock: __launch_bounds__(512,4) caps VGPR at 128 => >=2 blocks/CU
//   guaranteed => all 512 blocks co-resident (2 x 256 CUs).
//   No flag-reset needed: the harness's 268 MB poison covers flags+ws in one
//   fill (flags != SENT after poison). If an iteration is not re-poisoned,
//   flags retain SENT and ws retains last iteration's bytes — identical
//   (same W => same prep output), so early pass-through is value-benign.
//   The spin hides under the BW-bound encode (~2.7 us) => ~free.
//   Encode hist unchanged from R3 (native ds_add_u32, verified 97.1 us).
// ---------------------------------------------------------------------------
__global__ __launch_bounds__(512, 4)
void snn_mega_kernel(const float* __restrict__ x,
                     const float* __restrict__ W1raw, const float* __restrict__ W2raw,
                     const float* __restrict__ W3raw,
                     half_t* __restrict__ ws1, const float* __restrict__ b1,
                     half_t* __restrict__ ws2, const float* __restrict__ b2,
                     half_t* __restrict__ ws3, const float* __restrict__ b3,
                     unsigned* __restrict__ flags,
                     float* __restrict__ out) {
    __shared__ __align__(16) char smem[SMEM_TOTAL];
    float*  curT = (float*) (smem + SMEM_CUR);   // also hist/minmax scratch
    half_t* As   = (half_t*)(smem + SMEM_AS);    // aliases spk (As dead first)
    half_t* spk  = (half_t*)(smem + SMEM_SPK);

    const int tid  = threadIdx.x;
    const int b    = blockIdx.x;
    const int wave = tid >> 6;
    const int lane = tid & 63;

    // ---- fused prep, part 1: issue this block's weight-element load early
    // (1 elem/thread; HBM-cold latency overlaps the x burst below)
    float wprep = 0.0f;
    if (tid < 256) {
        int e = b * 256 + tid;                   // 512 blocks x 256 = 131072
        wprep = (b < 128) ? W1raw[e]
              : (b < 384) ? W2raw[e - H1 * F_INPUT]
                          : W3raw[e - H1 * F_INPUT - H2 * H1];
    }

    // ================= phase 0: latency encode (threads 0..255) ===========
    const int f  = tid & 127;
    const int sh = (tid >> 7) & 1;               // s-half: 0 -> s 0..31, 1 -> 32..63
    const float* xp = x + (size_t)b * (S_SZ * F_INPUT) + (size_t)sh * 32 * F_INPUT + f;
    float* scratch = curT;

    float v[32];                                 // gated x, registers (no spill:
                                                 // kernel peak pressure is the
                                                 // ~110-VGPR GEMM phase, cap 128)
    if (tid < 256) {
        // burst all 32 loads (independent, all in flight), gate at ENC_THR
#pragma unroll
        for (int s = 0; s < 32; ++s) {
            float val = xp[(size_t)s * F_INPUT];
            v[s] = (val < 0.75f) ? 0.0f : val;
        }
        float mn = 1e30f, mx = -1e30f;
#pragma unroll
        for (int s = 0; s < 32; ++s) {
            mn = fminf(mn, v[s]);
            mx = fmaxf(mx, v[s]);
        }
        scratch[sh * 128 + f]       = mn;
        scratch[256 + sh * 128 + f] = mx;

        // ---- fused prep, part 2: split + swizzled store (exact same math
        // and ws layout as the old prep_w_kernel -> bit-identical ws bytes)
        int e = b * 256 + tid;
        if (b < 128) {
            split_store_sw(wprep, ws1, e / F_INPUT, e % F_INPUT, F_INPUT / 32);
        } else if (b < 384) {
            int i = e - H1 * F_INPUT;
            split_store_sw(wprep, ws2, i / H1, i % H1, H1 / 32);
        } else {
            int i = e - H1 * F_INPUT - H2 * H1;
            split_store_sw(wprep, ws3, i / H2, i % H2, H2 / 32);
        }
    }
    __syncthreads();   // drains every wave's vmcnt -> all prep stores in L2
    if (tid == 0)      // release: L2 writeback, then flag visible device-wide
        __hip_atomic_store(&flags[b], PREP_SENT, __ATOMIC_RELEASE,
                           __HIP_MEMORY_SCOPE_AGENT);

    // exact: min(min half0, min half1) == min(all); same for max
    float fmn = fminf(scratch[f], scratch[128 + f]);
    float fmx = fmaxf(scratch[256 + f], scratch[384 + f]);
    __syncthreads();

    unsigned* histu = (unsigned*)scratch;        // hist[2][32][128] u32
    if (tid < 256) {
#pragma unroll
        for (int t = 0; t < T_STEPS; ++t) histu[sh * 4096 + t * 128 + f] = 0u;
        // no barrier needed: each thread touches only its own (sh,*,f) cells
        const float denom = fmx - fmn + 1e-8f;
#pragma unroll
        for (int s = 0; s < 32; ++s) {
            float g = v[s];                      // reuse register value
            float xn = (g - fmn) / denom;
            float d  = fmaxf(xn, 0.0100001f);        // clip(xn, LAT_THR+EPS)
            float tt = logf(d / (d - 0.01f));        // log latency code
            tt = tt * 31.0f;
            tt = tt / 11.512935464920229f;           // float32(log((thr+eps)/eps))
            float tr = rintf(tt);                    // half-to-even == jnp.round
            tr = fminf(fmaxf(tr, 0.0f), 31.0f);
            // native ds_add_u32 (no return, no CAS loop) — verified R3
            atomicAdd(&histu[sh * 4096 + (int)tr * 128 + f], 1u);
        }
    }
    __syncthreads();

    // merge halves -> rates (exact k/64) into As[t][f]; all 512 threads
#pragma unroll
    for (int i = 0; i < 8; ++i) {
        int idx = tid + i * 512;                 // 0..4095
        int t = idx >> 7, ff = idx & 127;
        float cnt = (float)(histu[t * 128 + ff] + histu[4096 + t * 128 + ff]);
        As[t * AS_STRIDE + ff] = (half_t)(cnt * 0.015625f);
    }
    __syncthreads();

    // ---- wait for ALL blocks' prep (thread t polls block t's flag).
    // Co-residency guaranteed (>=2 blocks/CU x 256 CU = 512). By now every
    // block has had ~the whole encode phase to finish its 1-elem prep, so
    // this normally passes on the first poll.
    while (__hip_atomic_load(&flags[tid], __ATOMIC_RELAXED,
                             __HIP_MEMORY_SCOPE_AGENT) != PREP_SENT)
        __builtin_amdgcn_s_sleep(2);
    __syncthreads();                                        // all 512 flags seen
    __builtin_amdgcn_fence(__ATOMIC_ACQUIRE, "agent");      // inv L1/stale L2

    // ================= layer 1: GEMM (K=128, N=256) + LIF =================
    gemm_phase<F_INPUT / 32, 2, AS_STRIDE>(ws1, b1, As, curT, wave, lane);
    __syncthreads();   // all As reads done; spk may now overwrite As region
    if (tid < 256) {
#pragma clang fp contract(off)
        const int h = tid;
        float mem = 0.0f;
#pragma unroll
        for (int t = 0; t < T_STEPS; ++t) {
            float c = curT[t * CUR_STRIDE + h];
            float reset = (mem - 1.0f > 0.0f) ? 1.0f : 0.0f;
            float p = 0.9f * mem;
            p = p + c;
            mem = p - reset;
            spk[t * SPK_STRIDE + h] = (half_t)((mem - 1.0f > 0.0f) ? 1.0f : 0.0f);
        }
    }
    __syncthreads();

    // ================= layer 2: GEMM (K=256, N=256) + LIF =================
    gemm_phase<H1 / 32, 2, SPK_STRIDE>(ws2, b2, spk, curT, wave, lane);
    __syncthreads();
    if (tid < 256) {
#pragma clang fp contract(off)
        const int h = tid;
        float mem = 0.0f;
#pragma unroll
        for (int t = 0; t < T_STEPS; ++t) {
            float c = curT[t * CUR_STRIDE + h];
            float reset = (mem - 1.0f > 0.0f) ? 1.0f : 0.0f;
            float p = 0.9f * mem;
            p = p + c;
            mem = p - reset;
            spk[t * SPK_STRIDE + h] = (half_t)((mem - 1.0f > 0.0f) ? 1.0f : 0.0f);
        }
    }
    __syncthreads();

    // ================= layer 3: GEMM (K=256, N=128) + LIF -> out ==========
    gemm_phase<H2 / 32, 1, SPK_STRIDE>(ws3, b3, spk, curT, wave, lane);
    __syncthreads();
    if (tid < H3) {
#pragma clang fp contract(off)
        const int h = tid;
        float mem = 0.0f;
#pragma unroll
        for (int t = 0; t < T_STEPS; ++t) {
            float c = curT[t * CUR_STRIDE + h];
            float reset = (mem - 1.0f > 0.0f) ? 1.0f : 0.0f;
            float p = 0.9f * mem;
            p = p + c;
            mem = p - reset;
            // reference output layout: [t*B + b][h], f32
            out[((size_t)t * B_SZ + b) * H3 + h] = (mem - 1.0f > 0.0f) ? 1.0f : 0.0f;
        }
    }
}

// ---------------------------------------------------------------------------
extern "C" void kernel_launch(void* const* d_in, const int* in_sizes, int n_in,
                              void* d_out, int out_size, void* d_ws, size_t ws_size,
                              hipStream_t stream) {
    const float* x  = (const float*)d_in[0];
    const float* W1 = (const float*)d_in[1];
    const float* b1 = (const float*)d_in[2];
    const float* W2 = (const float*)d_in[3];
    const float* b2 = (const float*)d_in[4];
    const float* W3 = (const float*)d_in[5];
    const float* b3 = (const float*)d_in[6];
    float* out = (float*)d_out;

    char* ws = (char*)d_ws;
    half_t*   ws1   = (half_t*)ws;                      // 128 KB (swizzled hi/lo)
    half_t*   ws2   = (half_t*)(ws + 128 * 1024);       // 256 KB
    half_t*   ws3   = (half_t*)(ws + 384 * 1024);       // 128 KB
    unsigned* flags = (unsigned*)(ws + 512 * 1024);     // 512 x u32 prep flags

    // single dispatch: prep fused into the mega kernel (flag-ordered)
    snn_mega_kernel<<<B_SZ, 512, 0, stream>>>(x, W1, W2, W3,
                                              ws1, b1, ws2, b2, ws3, b3,
                                              flags, out);
}

// Round 5
// 97.017 us; speedup vs baseline: 1.3523x; 1.3523x over previous
//
#include <hip/hip_runtime.h>
#include <cstddef>

// Problem constants (match reference)
#define T_STEPS 32
#define B_SZ    512
#define S_SZ    64
#define F_INPUT 128
#define H1      256
#define H2      256
#define H3      128

typedef _Float16 half_t;
typedef __attribute__((ext_vector_type(8))) _Float16 half8;
typedef __attribute__((ext_vector_type(4))) float   float4v;

// ---------------------------------------------------------------------------
// Kernel 0: pre-split + SWIZZLE weights into MFMA-fragment order (verified
// exact since R6).
//   hi = f16(w) (flushed if f16-denormal), lo = f16((w - hi) * 2^12)
// Tile (n_tile, k_chunk) = 1024 halfs: [0,512) hi, [512,1024) lo, element
// (lr=n&15, quad=kin>>3, j=kin&7) at (quad*16+lr)*8 + j.
// Wave B-frag load = base + lane*8 -> 1 KB fully coalesced, L2-resident.
// R5 CHANGE (only change vs verified-97.1us R3): 4 elems/thread via one
// float4 load (layer boundaries 32768/98304 are 4-aligned -> no straddle;
// per-element math and store layout identical -> bit-identical ws bytes).
// R4's single-dispatch flag-sync fusion is permanently abandoned: its
// agent-scope acquire fence invalidated L2, forcing every block's ~512 KB
// weight re-read to L3 (~256 MB/iter, +25 us) — worse than the ~3 us
// dispatch it saved.
// ---------------------------------------------------------------------------
__device__ inline void split_store_sw(float w, half_t* out, int n, int k, int kchunks) {
    half_t hi = (half_t)w;
    float hif = (float)hi;
    if (fabsf(hif) < 6.103515625e-05f) { hi = (half_t)0.0f; hif = 0.0f; }
    half_t lo = (half_t)((w - hif) * 4096.0f);
    int n_tile = n >> 4, lr = n & 15;
    int k_chunk = k >> 5, kin = k & 31, quad = kin >> 3, j = kin & 7;
    size_t base = (size_t)(n_tile * kchunks + k_chunk) * 1024;
    size_t off  = base + (size_t)((quad << 4) + lr) * 8 + j;
    out[off]       = hi;
    out[off + 512] = lo;
}

__global__ __launch_bounds__(256)
void prep_w_kernel(const float* __restrict__ W1, const float* __restrict__ W2,
                   const float* __restrict__ W3,
                   half_t* __restrict__ ws1, half_t* __restrict__ ws2,
                   half_t* __restrict__ ws3) {
    int e0 = (blockIdx.x * blockDim.x + threadIdx.x) * 4;   // 0..131068, step 4
    // one vectorized read of 4 consecutive weights (same layer: boundaries
    // at H1*F_INPUT=32768 and +H2*H1=98304 are both multiples of 4)
    float4v w4;
    if (e0 < H1 * F_INPUT) {
        w4 = *(const float4v*)(W1 + e0);
#pragma unroll
        for (int i = 0; i < 4; ++i) {
            int e = e0 + i;
            split_store_sw(w4[i], ws1, e / F_INPUT, e % F_INPUT, F_INPUT / 32);
        }
    } else if (e0 < H1 * F_INPUT + H2 * H1) {
        int i0 = e0 - H1 * F_INPUT;
        w4 = *(const float4v*)(W2 + i0);
#pragma unroll
        for (int i = 0; i < 4; ++i) {
            int e = i0 + i;
            split_store_sw(w4[i], ws2, e / H1, e % H1, H1 / 32);
        }
    } else {
        int i0 = e0 - H1 * F_INPUT - H2 * H1;
        w4 = *(const float4v*)(W3 + i0);
#pragma unroll
        for (int i = 0; i < 4; ++i) {
            int e = i0 + i;
            split_store_sw(w4[i], ws3, e / H2, e % H2, H2 / 32);
        }
    }
}

// ---------------------------------------------------------------------------
// LDS geometry (unchanged from R7/R9): spk aliases As; 49 KB -> 2 blocks/CU.
// ---------------------------------------------------------------------------
#define CUR_STRIDE 260   // floats; cur tile [32][CUR_STRIDE] (also hist scratch)
#define AS_STRIDE  136   // halfs;  rates  [32][AS_STRIDE]
#define SPK_STRIDE 264   // halfs;  spikes [32][SPK_STRIDE]
#define SMEM_CUR   0                      // 32*260*4 = 33280 B
#define SMEM_AS    33280                  // As: 8704 B  } aliased: max = 16896
#define SMEM_SPK   33280                  // spk: 16896 B}
#define SMEM_TOTAL 50176                  // 49 KB; x2 blocks/CU = 98 KB < 160

// GEMM phase (unchanged from R9): C = sum A*(hi + 2^-12 lo) + bias, depth-1
// W prefetch, per-accumulator MFMA order fixed -> bit-identical across rounds.
template<int KCHUNKS, int NT, int ASTRIDE>
__device__ __forceinline__ void gemm_phase(const half_t* __restrict__ Wsw,
                                           const float*  __restrict__ bias,
                                           const half_t* __restrict__ Als,
                                           float* __restrict__ curT,
                                           int wave, int lane) {
    const int quad = lane >> 4, lr = lane & 15;
    float4v acc_h[2][NT], acc_l[2][NT];
#pragma unroll
    for (int mt = 0; mt < 2; ++mt)
#pragma unroll
        for (int nt = 0; nt < NT; ++nt) {
            acc_h[mt][nt] = (float4v){0.0f, 0.0f, 0.0f, 0.0f};
            acc_l[mt][nt] = (float4v){0.0f, 0.0f, 0.0f, 0.0f};
        }

    half8 wh[NT], wl[NT];
#pragma unroll
    for (int nt = 0; nt < NT; ++nt) {
        const half_t* p = Wsw + ((size_t)(wave * NT + nt) * KCHUNKS) * 1024 + lane * 8;
        wh[nt] = *(const half8*)(p);
        wl[nt] = *(const half8*)(p + 512);
    }

#pragma unroll
    for (int c = 0; c < KCHUNKS; ++c) {
        half8 a0 = *(const half8*)(Als + lr * ASTRIDE        + c * 32 + quad * 8);
        half8 a1 = *(const half8*)(Als + (16 + lr) * ASTRIDE + c * 32 + quad * 8);
        half8 nwh[NT], nwl[NT];
        if (c + 1 < KCHUNKS) {
#pragma unroll
            for (int nt = 0; nt < NT; ++nt) {
                const half_t* p =
                    Wsw + ((size_t)(wave * NT + nt) * KCHUNKS + c + 1) * 1024 + lane * 8;
                nwh[nt] = *(const half8*)(p);
                nwl[nt] = *(const half8*)(p + 512);
            }
        }
#pragma unroll
        for (int nt = 0; nt < NT; ++nt) {
            acc_h[0][nt] = __builtin_amdgcn_mfma_f32_16x16x32_f16(a0, wh[nt], acc_h[0][nt], 0, 0, 0);
            acc_h[1][nt] = __builtin_amdgcn_mfma_f32_16x16x32_f16(a1, wh[nt], acc_h[1][nt], 0, 0, 0);
            acc_l[0][nt] = __builtin_amdgcn_mfma_f32_16x16x32_f16(a0, wl[nt], acc_l[0][nt], 0, 0, 0);
            acc_l[1][nt] = __builtin_amdgcn_mfma_f32_16x16x32_f16(a1, wl[nt], acc_l[1][nt], 0, 0, 0);
        }
#pragma unroll
        for (int nt = 0; nt < NT; ++nt) { wh[nt] = nwh[nt]; wl[nt] = nwl[nt]; }
    }

    // epilogue -> curT (C/D layout: col=lane&15, row=quad*4+reg)
#pragma unroll
    for (int nt = 0; nt < NT; ++nt) {
        int col = wave * NT * 16 + nt * 16 + lr;
        float bj = bias[col];
#pragma unroll
        for (int mt = 0; mt < 2; ++mt) {
            int rbase = mt * 16 + quad * 4;
#pragma unroll
            for (int r = 0; r < 4; ++r) {
                float v = acc_h[mt][nt][r] + 2.44140625e-04f * acc_l[mt][nt][r];
                curT[(rbase + r) * CUR_STRIDE + col] = v + bj;
            }
        }
    }
}

// ---------------------------------------------------------------------------
// Mega kernel: one block = one batch b, 512 threads (8 waves).
// Byte-identical to the verified 97.1 us R3 kernel (native ds_add_u32 hist;
// R4's fused-prep + flag-sync removed — see prep_w comment for why).
// ---------------------------------------------------------------------------
__global__ __launch_bounds__(512, 4)
void snn_mega_kernel(const float* __restrict__ x,
                     const half_t* __restrict__ ws1, const float* __restrict__ b1,
                     const half_t* __restrict__ ws2, const float* __restrict__ b2,
                     const half_t* __restrict__ ws3, const float* __restrict__ b3,
                     float* __restrict__ out) {
    __shared__ __align__(16) char smem[SMEM_TOTAL];
    float*  curT = (float*) (smem + SMEM_CUR);   // also hist/minmax scratch
    half_t* As   = (half_t*)(smem + SMEM_AS);    // aliases spk (As dead first)
    half_t* spk  = (half_t*)(smem + SMEM_SPK);

    const int tid  = threadIdx.x;
    const int b    = blockIdx.x;
    const int wave = tid >> 6;
    const int lane = tid & 63;

    // ================= phase 0: latency encode (threads 0..255) ===========
    const int f  = tid & 127;
    const int sh = (tid >> 7) & 1;               // s-half: 0 -> s 0..31, 1 -> 32..63
    const float* xp = x + (size_t)b * (S_SZ * F_INPUT) + (size_t)sh * 32 * F_INPUT + f;
    float* scratch = curT;

    float v[32];                                 // gated x, registers
    if (tid < 256) {
        // burst all 32 loads (independent, all in flight), gate at ENC_THR
#pragma unroll
        for (int s = 0; s < 32; ++s) {
            float val = xp[(size_t)s * F_INPUT];
            v[s] = (val < 0.75f) ? 0.0f : val;
        }
        float mn = 1e30f, mx = -1e30f;
#pragma unroll
        for (int s = 0; s < 32; ++s) {
            mn = fminf(mn, v[s]);
            mx = fmaxf(mx, v[s]);
        }
        scratch[sh * 128 + f]       = mn;
        scratch[256 + sh * 128 + f] = mx;
    }
    __syncthreads();
    // exact: min(min half0, min half1) == min(all); same for max
    float fmn = fminf(scratch[f], scratch[128 + f]);
    float fmx = fmaxf(scratch[256 + f], scratch[384 + f]);
    __syncthreads();

    unsigned* histu = (unsigned*)scratch;        // hist[2][32][128] u32
    if (tid < 256) {
#pragma unroll
        for (int t = 0; t < T_STEPS; ++t) histu[sh * 4096 + t * 128 + f] = 0u;
        // no barrier needed: each thread touches only its own (sh,*,f) cells
        const float denom = fmx - fmn + 1e-8f;
#pragma unroll
        for (int s = 0; s < 32; ++s) {
            float g = v[s];                      // reuse register value
            float xn = (g - fmn) / denom;
            float d  = fmaxf(xn, 0.0100001f);        // clip(xn, LAT_THR+EPS)
            float tt = logf(d / (d - 0.01f));        // log latency code
            tt = tt * 31.0f;
            tt = tt / 11.512935464920229f;           // float32(log((thr+eps)/eps))
            float tr = rintf(tt);                    // half-to-even == jnp.round
            tr = fminf(fmaxf(tr, 0.0f), 31.0f);
            // native ds_add_u32 (no return, no CAS loop) — verified R3
            atomicAdd(&histu[sh * 4096 + (int)tr * 128 + f], 1u);
        }
    }
    __syncthreads();

    // merge halves -> rates (exact k/64) into As[t][f]; all 512 threads
#pragma unroll
    for (int i = 0; i < 8; ++i) {
        int idx = tid + i * 512;                 // 0..4095
        int t = idx >> 7, ff = idx & 127;
        float cnt = (float)(histu[t * 128 + ff] + histu[4096 + t * 128 + ff]);
        As[t * AS_STRIDE + ff] = (half_t)(cnt * 0.015625f);
    }
    __syncthreads();

    // ================= layer 1: GEMM (K=128, N=256) + LIF =================
    gemm_phase<F_INPUT / 32, 2, AS_STRIDE>(ws1, b1, As, curT, wave, lane);
    __syncthreads();   // all As reads done; spk may now overwrite As region
    if (tid < 256) {
#pragma clang fp contract(off)
        const int h = tid;
        float mem = 0.0f;
#pragma unroll
        for (int t = 0; t < T_STEPS; ++t) {
            float c = curT[t * CUR_STRIDE + h];
            float reset = (mem - 1.0f > 0.0f) ? 1.0f : 0.0f;
            float p = 0.9f * mem;
            p = p + c;
            mem = p - reset;
            spk[t * SPK_STRIDE + h] = (half_t)((mem - 1.0f > 0.0f) ? 1.0f : 0.0f);
        }
    }
    __syncthreads();

    // ================= layer 2: GEMM (K=256, N=256) + LIF =================
    gemm_phase<H1 / 32, 2, SPK_STRIDE>(ws2, b2, spk, curT, wave, lane);
    __syncthreads();
    if (tid < 256) {
#pragma clang fp contract(off)
        const int h = tid;
        float mem = 0.0f;
#pragma unroll
        for (int t = 0; t < T_STEPS; ++t) {
            float c = curT[t * CUR_STRIDE + h];
            float reset = (mem - 1.0f > 0.0f) ? 1.0f : 0.0f;
            float p = 0.9f * mem;
            p = p + c;
            mem = p - reset;
            spk[t * SPK_STRIDE + h] = (half_t)((mem - 1.0f > 0.0f) ? 1.0f : 0.0f);
        }
    }
    __syncthreads();

    // ================= layer 3: GEMM (K=256, N=128) + LIF -> out ==========
    gemm_phase<H2 / 32, 1, SPK_STRIDE>(ws3, b3, spk, curT, wave, lane);
    __syncthreads();
    if (tid < H3) {
#pragma clang fp contract(off)
        const int h = tid;
        float mem = 0.0f;
#pragma unroll
        for (int t = 0; t < T_STEPS; ++t) {
            float c = curT[t * CUR_STRIDE + h];
            float reset = (mem - 1.0f > 0.0f) ? 1.0f : 0.0f;
            float p = 0.9f * mem;
            p = p + c;
            mem = p - reset;
            // reference output layout: [t*B + b][h], f32
            out[((size_t)t * B_SZ + b) * H3 + h] = (mem - 1.0f > 0.0f) ? 1.0f : 0.0f;
        }
    }
}

// ---------------------------------------------------------------------------
extern "C" void kernel_launch(void* const* d_in, const int* in_sizes, int n_in,
                              void* d_out, int out_size, void* d_ws, size_t ws_size,
                              hipStream_t stream) {
    const float* x  = (const float*)d_in[0];
    const float* W1 = (const float*)d_in[1];
    const float* b1 = (const float*)d_in[2];
    const float* W2 = (const float*)d_in[3];
    const float* b2 = (const float*)d_in[4];
    const float* W3 = (const float*)d_in[5];
    const float* b3 = (const float*)d_in[6];
    float* out = (float*)d_out;

    char* ws = (char*)d_ws;
    half_t* ws1 = (half_t*)ws;                          // 128 KB (swizzled hi/lo)
    half_t* ws2 = (half_t*)(ws + 128 * 1024);           // 256 KB
    half_t* ws3 = (half_t*)(ws + 384 * 1024);           // 128 KB

    // 0. split + swizzle weights (one dispatch, 4 elems/thread, float4 reads)
    prep_w_kernel<<<(H1 * F_INPUT + H2 * H1 + H3 * H2) / 1024, 256, 0, stream>>>(
        W1, W2, W3, ws1, ws2, ws3);

    // 1. whole network: one block per batch, 8 waves, spikes stay in LDS
    snn_mega_kernel<<<B_SZ, 512, 0, stream>>>(x, ws1, b1, ws2, b2, ws3, b3, out);
}